// Round 10
// baseline (31.440 us; speedup 1.0000x reference)
//
#include <hip/hip_runtime.h>
#include <math.h>

#define N  2048
#define K  8
#define NK 1024
#define R  4             // rows per block (maps reused across rows)
#define TPB 512
#define TAU_C 0.5f
#define TAU_S 0.5f

// ---- macros keep everything straight-line & statically indexed (rule #20) ----

// Load row rr's per-client row-positions into SGPRs and issue ALL its gathers
// into vr (double-buffered). sched_barrier pins issue order: these loads go
// out BEFORE the previous row's stats execute -> latency overlapped.
#define LOAD_ROW(rr, ixr, kp, vr)                                              \
    {                                                                          \
        kp = 0;                                                                \
        _Pragma("unroll")                                                      \
        for (int k = 0; k < K; ++k) {                                          \
            int v_ = (int)ixs[k][rr];                 /* uniform LDS read */   \
            ixr[k] = __builtin_amdgcn_readfirstlane(v_);                       \
            kp |= (ixr[k] >= 0) ? (1 << k) : 0;                                \
        }                                                                      \
        _Pragma("unroll")                                                      \
        for (int k = 0; k < K; ++k) {                                          \
            if (ixr[k] >= 0) {                        /* SGPR branch */        \
                const float* __restrict__ bk_ =                                \
                    adj + ((size_t)k * NK + (size_t)ixr[k]) * NK;              \
                _Pragma("unroll")                                              \
                for (int yy = 0; yy < 4; ++yy)                                 \
                    vr[yy][k] = bk_[jc[k][yy]];       /* consecutive-j */      \
            }                                                                  \
        }                                                                      \
        __builtin_amdgcn_sched_barrier(0);                                     \
    }

// Exact f32 rounding sequence of the reference (R1/R3-R6/R8/R9 proven:
// absmax 0.0). No fast path (R7 lesson). Absent-k lanes masked via m.
#define STATS_ROW(rr, kp, vr)                                                  \
    {                                                                          \
        float res[4];                                                          \
        _Pragma("unroll")                                                      \
        for (int yy = 0; yy < 4; ++yy) {                                       \
            const int m = jmask[yy] & kp;                                      \
            float sum = 0.f;                                                   \
            _Pragma("unroll")                                                  \
            for (int k = 0; k < K; ++k) {                                      \
                bool p = (m >> k) & 1;                                         \
                sum += p ? vr[yy][k] : 0.f;           /* ordered, masked */    \
            }                                                                  \
            float cnt  = (float)__popc(m);                                     \
            float n    = fmaxf(cnt, 1e-5f);                                    \
            float mean = sum / n;                     /* IEEE divide */        \
            float cs = 0.f, vs = 0.f;                                          \
            _Pragma("unroll")                                                  \
            for (int k = 0; k < K; ++k) {                                      \
                bool  p = (m >> k) & 1;                                        \
                float a = p ? vr[yy][k] : 0.f;                                 \
                cs += (p && (a > TAU_C)) ? 1.f : 0.f;                          \
                float d = a - mean;                                            \
                vs += p ? d * d : 0.f;                /* select blocks fma */  \
            }                                                                  \
            float C = cs / n;                         /* IEEE divide */        \
            float V = vs / n;                         /* IEEE divide */        \
            float S = C * expf(-V);                   /* precise expf */       \
            float rr_ = (S > TAU_S) ? mean : 0.f;                              \
            res[yy] = (cnt > 0.f) ? rr_ : 0.f;                                 \
        }                                                                      \
        float4 o_;                                                             \
        o_.x = res[0]; o_.y = res[1]; o_.z = res[2]; o_.w = res[3];            \
        *(float4*)(out + (size_t)(X0 + rr) * N + y0) = o_;                     \
    }

// Single fused kernel (replay-safe per R8): block rebuilds index maps from the
// immutable input `idx` into LDS, then serves R=4 full output rows with a
// 2-deep software pipeline: row r+1's gathers fly during row r's stats.
__global__ void __launch_bounds__(TPB, 4)
fia_fused(const float* __restrict__ adj,
          const int*   __restrict__ idx,
          float* __restrict__ out) {
    __shared__ short jj[K][N];       // 32 KB: position of y in idx[k], or -1
    __shared__ short ixs[K][R];      // position of row x in idx[k], or -1

    const int tid = threadIdx.x;
    const int X0  = blockIdx.x * R;

    // ---- init maps to -1 (every jj cell has a unique scan-writer)
    {
        int4  m1 = make_int4(-1, -1, -1, -1);
        int4* p4 = (int4*)&jj[0][0];                 // K*N*2/16 = 2048 int4
        #pragma unroll
        for (int q = 0; q < (K * N * 2) / (16 * TPB); ++q)   // 4
            p4[q * TPB + tid] = m1;
        if (tid < K * R) ((short*)ixs)[tid] = (short)-1;
    }
    __syncthreads();

    // ---- scan idx (8192 entries, coalesced). Unique writer per cell.
    #pragma unroll
    for (int it = 0; it < (K * NK) / TPB; ++it) {    // 16
        int t   = it * TPB + tid;
        int val = idx[t];                            // coalesced
        int k   = t >> 10;                           // uniform per iteration
        int p   = t & (NK - 1);
        jj[k][val] = (short)p;
        int rel = val - X0;
        if ((unsigned)rel < (unsigned)R) ixs[k][rel] = (short)p;
    }
    __syncthreads();

    // ---- per-thread column state, hoisted (reused by all R rows)
    const int y0 = tid * 4;                          // 4 consecutive columns
    int jc[K][4];                                    // clamped j
    int jmask[4] = {0, 0, 0, 0};
    #pragma unroll
    for (int k = 0; k < K; ++k) {
        short4 v = *(const short4*)&jj[k][y0];       // ds_read_b64
        int j0 = v.x, j1 = v.y, j2 = v.z, j3 = v.w;
        jmask[0] |= (j0 >= 0) ? (1 << k) : 0;
        jmask[1] |= (j1 >= 0) ? (1 << k) : 0;
        jmask[2] |= (j2 >= 0) ? (1 << k) : 0;
        jmask[3] |= (j3 >= 0) ? (1 << k) : 0;
        jc[k][0] = j0 & ~(j0 >> 31);                 // max(j,0)
        jc[k][1] = j1 & ~(j1 >> 31);
        jc[k][2] = j2 & ~(j2 >> 31);
        jc[k][3] = j3 & ~(j3 >> 31);
    }

    // ---- 2-deep pipelined row processing (R = 4, fully unrolled)
    int   ixA[K], ixB[K], kpA, kpB;
    float vrA[4][K] = {};                            // one-time zero-init:
    float vrB[4][K] = {};                            // absent-k regs stay masked

    LOAD_ROW(0, ixA, kpA, vrA);                      // row 0 gathers in flight
    LOAD_ROW(1, ixB, kpB, vrB);                      // row 1 gathers in flight
    STATS_ROW(0, kpA, vrA);                          // waits only on A's loads
    LOAD_ROW(2, ixA, kpA, vrA);                      // row 2 flies during...
    STATS_ROW(1, kpB, vrB);                          // ...row 1 stats
    LOAD_ROW(3, ixB, kpB, vrB);                      // row 3 flies during...
    STATS_ROW(2, kpA, vrA);                          // ...row 2 stats
    STATS_ROW(3, kpB, vrB);
}

extern "C" void kernel_launch(void* const* d_in, const int* in_sizes, int n_in,
                              void* d_out, int out_size, void* d_ws, size_t ws_size,
                              hipStream_t stream) {
    const float* adj = (const float*)d_in[0];        // (K, NK, NK) f32
    const int*   idx = (const int*)d_in[1];          // (K, NK) i32
    float*       out = (float*)d_out;                // (N, N) f32

    dim3 block(TPB, 1, 1);
    dim3 grid(N / R, 1, 1);                          // 512 blocks x 4 rows
    fia_fused<<<grid, block, 0, stream>>>(adj, idx, out);
}